// Round 1
// baseline (1399.361 us; speedup 1.0000x reference)
//
#include <hip/hip_runtime.h>

#define NUM_NODES 100000
#define IN_F 256
#define OUT_F 128

// ---------------------------------------------------------------------------
// Kernel 1: support = X @ W ; out = support + bias  (fused epilogue)
// Tile: 64 rows x 128 cols (all of OUT_F), BK=32. 256 threads, each thread
// computes a 4x8 sub-tile. Classic LDS-staged fp32 SIMT GEMM (no fp32 MFMA
// on CDNA4).
// ---------------------------------------------------------------------------
__global__ __launch_bounds__(256) void gemm_bias_kernel(
    const float* __restrict__ x, const float* __restrict__ w,
    const float* __restrict__ bias, float* __restrict__ support,
    float* __restrict__ out)
{
    __shared__ float As[64][33];   // +1 pad breaks bank-conflict on column reads
    __shared__ float Bs[32][128];

    const int tid = threadIdx.x;
    const int tx = tid & 15;       // 16 col-groups of 8
    const int ty = tid >> 4;       // 16 row-groups of 4
    const int block_row = blockIdx.x * 64;

    float acc[4][8];
#pragma unroll
    for (int i = 0; i < 4; ++i)
#pragma unroll
        for (int j = 0; j < 8; ++j) acc[i][j] = 0.f;

    for (int k0 = 0; k0 < IN_F; k0 += 32) {
        // Stage A tile: 64x32 floats = 512 float4; 2 per thread.
#pragma unroll
        for (int i = 0; i < 2; ++i) {
            int idx = tid + i * 256;
            int r = idx >> 3;              // 8 float4 per row of 32
            int c4 = (idx & 7) << 2;
            int grow = block_row + r;
            float4 v = {0.f, 0.f, 0.f, 0.f};
            if (grow < NUM_NODES)
                v = *reinterpret_cast<const float4*>(x + (size_t)grow * IN_F + k0 + c4);
            As[r][c4 + 0] = v.x; As[r][c4 + 1] = v.y;
            As[r][c4 + 2] = v.z; As[r][c4 + 3] = v.w;
        }
        // Stage B tile: 32x128 floats = 1024 float4; 4 per thread.
#pragma unroll
        for (int i = 0; i < 4; ++i) {
            int idx = tid + i * 256;
            int r = idx >> 5;              // 32 float4 per row of 128
            int c4 = (idx & 31) << 2;
            *reinterpret_cast<float4*>(&Bs[r][c4]) =
                *reinterpret_cast<const float4*>(w + (size_t)(k0 + r) * OUT_F + c4);
        }
        __syncthreads();

#pragma unroll
        for (int k = 0; k < 32; ++k) {
            float a[4];
#pragma unroll
            for (int i = 0; i < 4; ++i) a[i] = As[ty * 4 + i][k];
            float4 b0 = *reinterpret_cast<const float4*>(&Bs[k][tx * 8]);
            float4 b1 = *reinterpret_cast<const float4*>(&Bs[k][tx * 8 + 4]);
            float b[8] = {b0.x, b0.y, b0.z, b0.w, b1.x, b1.y, b1.z, b1.w};
#pragma unroll
            for (int i = 0; i < 4; ++i)
#pragma unroll
                for (int j = 0; j < 8; ++j)
                    acc[i][j] = fmaf(a[i], b[j], acc[i][j]);
        }
        __syncthreads();
    }

    // Epilogue: support -> ws, support+bias -> out (full overwrite of d_out).
    float4 bi0 = *reinterpret_cast<const float4*>(bias + tx * 8);
    float4 bi1 = *reinterpret_cast<const float4*>(bias + tx * 8 + 4);
#pragma unroll
    for (int i = 0; i < 4; ++i) {
        int grow = block_row + ty * 4 + i;
        if (grow >= NUM_NODES) continue;
        size_t off = (size_t)grow * OUT_F + tx * 8;
        float4 s0 = {acc[i][0], acc[i][1], acc[i][2], acc[i][3]};
        float4 s1 = {acc[i][4], acc[i][5], acc[i][6], acc[i][7]};
        *reinterpret_cast<float4*>(support + off) = s0;
        *reinterpret_cast<float4*>(support + off + 4) = s1;
        float4 o0 = {s0.x + bi0.x, s0.y + bi0.y, s0.z + bi0.z, s0.w + bi0.w};
        float4 o1 = {s1.x + bi1.x, s1.y + bi1.y, s1.z + bi1.z, s1.w + bi1.w};
        *reinterpret_cast<float4*>(out + off) = o0;
        *reinterpret_cast<float4*>(out + off + 4) = o1;
    }
}

// ---------------------------------------------------------------------------
// Kernel 2: out[col[e]] += support[row[e]] for every edge.
// One wave (64 lanes) per edge -> each lane handles 2 consecutive floats of
// the 128-wide row: coalesced 512 B gather + 2 fp32 atomicAdds per lane.
// row/col indices are wave-uniform (all 64 lanes read the same address ->
// broadcast).
// ---------------------------------------------------------------------------
__global__ __launch_bounds__(256) void scatter_kernel(
    const float* __restrict__ support, const int* __restrict__ ei,
    float* __restrict__ out, int E)
{
    const long long total = (long long)E * 64;
    const long long stride = (long long)gridDim.x * blockDim.x;
    for (long long t = (long long)blockIdx.x * blockDim.x + threadIdx.x;
         t < total; t += stride) {
        int e = (int)(t >> 6);
        int j = ((int)t & 63) * 2;
        int row = ei[e];
        int col = ei[E + e];
        float2 v = *reinterpret_cast<const float2*>(
            support + (size_t)row * OUT_F + j);
        atomicAdd(out + (size_t)col * OUT_F + j,     v.x);
        atomicAdd(out + (size_t)col * OUT_F + j + 1, v.y);
    }
}

extern "C" void kernel_launch(void* const* d_in, const int* in_sizes, int n_in,
                              void* d_out, int out_size, void* d_ws, size_t ws_size,
                              hipStream_t stream) {
    const float* x    = (const float*)d_in[0];
    const float* w    = (const float*)d_in[1];
    const float* bias = (const float*)d_in[2];
    const int*   ei   = (const int*)d_in[3];
    float* out = (float*)d_out;
    float* support = (float*)d_ws;       // needs NUM_NODES*OUT_F*4 = 51.2 MB
    const int E = in_sizes[3] / 2;

    dim3 grid1((NUM_NODES + 63) / 64);
    gemm_bias_kernel<<<grid1, 256, 0, stream>>>(x, w, bias, support, out);

    long long total = (long long)E * 64;
    long long want = (total + 255) / 256;
    int blocks = (int)(want < 8192 ? want : 8192);
    scatter_kernel<<<blocks, 256, 0, stream>>>(support, ei, out, E);
}

// Round 2
// 429.343 us; speedup vs baseline: 3.2593x; 3.2593x over previous
//
#include <hip/hip_runtime.h>

#define NUM_NODES 100000
#define IN_F 256
#define OUT_F 128
#define SCAN_BLK 1024   // elements scanned per block in scan1

// ---------------------------------------------------------------------------
// Kernel 1: support = X @ W   (support only; bias+self fused into aggregate)
// ---------------------------------------------------------------------------
__global__ __launch_bounds__(256) void gemm_kernel(
    const float* __restrict__ x, const float* __restrict__ w,
    float* __restrict__ support)
{
    __shared__ float As[64][33];
    __shared__ float Bs[32][128];

    const int tid = threadIdx.x;
    const int tx = tid & 15;
    const int ty = tid >> 4;
    const int block_row = blockIdx.x * 64;

    float acc[4][8];
#pragma unroll
    for (int i = 0; i < 4; ++i)
#pragma unroll
        for (int j = 0; j < 8; ++j) acc[i][j] = 0.f;

    for (int k0 = 0; k0 < IN_F; k0 += 32) {
#pragma unroll
        for (int i = 0; i < 2; ++i) {
            int idx = tid + i * 256;
            int r = idx >> 3;
            int c4 = (idx & 7) << 2;
            int grow = block_row + r;
            float4 v = {0.f, 0.f, 0.f, 0.f};
            if (grow < NUM_NODES)
                v = *reinterpret_cast<const float4*>(x + (size_t)grow * IN_F + k0 + c4);
            As[r][c4 + 0] = v.x; As[r][c4 + 1] = v.y;
            As[r][c4 + 2] = v.z; As[r][c4 + 3] = v.w;
        }
#pragma unroll
        for (int i = 0; i < 4; ++i) {
            int idx = tid + i * 256;
            int r = idx >> 5;
            int c4 = (idx & 31) << 2;
            *reinterpret_cast<float4*>(&Bs[r][c4]) =
                *reinterpret_cast<const float4*>(w + (size_t)(k0 + r) * OUT_F + c4);
        }
        __syncthreads();

#pragma unroll
        for (int k = 0; k < 32; ++k) {
            float a[4];
#pragma unroll
            for (int i = 0; i < 4; ++i) a[i] = As[ty * 4 + i][k];
            float4 b0 = *reinterpret_cast<const float4*>(&Bs[k][tx * 8]);
            float4 b1 = *reinterpret_cast<const float4*>(&Bs[k][tx * 8 + 4]);
            float b[8] = {b0.x, b0.y, b0.z, b0.w, b1.x, b1.y, b1.z, b1.w};
#pragma unroll
            for (int i = 0; i < 4; ++i)
#pragma unroll
                for (int j = 0; j < 8; ++j)
                    acc[i][j] = fmaf(a[i], b[j], acc[i][j]);
        }
        __syncthreads();
    }

#pragma unroll
    for (int i = 0; i < 4; ++i) {
        int grow = block_row + ty * 4 + i;
        if (grow >= NUM_NODES) continue;
        size_t off = (size_t)grow * OUT_F + tx * 8;
        float4 s0 = {acc[i][0], acc[i][1], acc[i][2], acc[i][3]};
        float4 s1 = {acc[i][4], acc[i][5], acc[i][6], acc[i][7]};
        *reinterpret_cast<float4*>(support + off) = s0;
        *reinterpret_cast<float4*>(support + off + 4) = s1;
    }
}

// ---------------------------------------------------------------------------
// CSR build: histogram -> scan -> rank scatter (int atomics on 400 KB only)
// ---------------------------------------------------------------------------
__global__ __launch_bounds__(256) void hist_kernel(
    const int* __restrict__ ei, int E, int* __restrict__ counts)
{
    int stride = gridDim.x * blockDim.x;
    for (int e = blockIdx.x * blockDim.x + threadIdx.x; e < E; e += stride)
        atomicAdd(&counts[ei[E + e]], 1);
}

// Per-block inclusive scan of SCAN_BLK elements (256 thr x 4), write
// inclusive sums to offsets[i+1], block total to bsums[b].
__global__ __launch_bounds__(256) void scan1_kernel(
    const int* __restrict__ counts, int* __restrict__ offsets,
    int* __restrict__ bsums, int n)
{
    __shared__ int lds[256];
    const int t = threadIdx.x;
    const int base = blockIdx.x * SCAN_BLK + t * 4;
    int v[4];
#pragma unroll
    for (int i = 0; i < 4; ++i) {
        int idx = base + i;
        v[i] = (idx < n) ? counts[idx] : 0;
    }
    v[1] += v[0]; v[2] += v[1]; v[3] += v[2];
    lds[t] = v[3];
    __syncthreads();
    for (int off = 1; off < 256; off <<= 1) {
        int xv = lds[t];
        int yv = (t >= off) ? lds[t - off] : 0;
        __syncthreads();
        lds[t] = xv + yv;
        __syncthreads();
    }
    int prev = (t > 0) ? lds[t - 1] : 0;
#pragma unroll
    for (int i = 0; i < 4; ++i) {
        int idx = base + i;
        if (idx < n) offsets[idx + 1] = v[i] + prev;
    }
    if (t == 255) bsums[blockIdx.x] = lds[255];
}

// Single block: exclusive scan of block sums (nb <= 128).
__global__ __launch_bounds__(128) void scan2_kernel(int* __restrict__ bsums, int nb)
{
    __shared__ int lds[128];
    const int t = threadIdx.x;
    lds[t] = (t < nb) ? bsums[t] : 0;
    __syncthreads();
    for (int off = 1; off < 128; off <<= 1) {
        int xv = lds[t];
        int yv = (t >= off) ? lds[t - off] : 0;
        __syncthreads();
        lds[t] = xv + yv;
        __syncthreads();
    }
    if (t < nb) bsums[t] = (t > 0) ? lds[t - 1] : 0;
}

// Add block offsets; produce final offsets[] and a working copy cursor[].
__global__ __launch_bounds__(256) void scan3_kernel(
    int* __restrict__ offsets, int* __restrict__ cursor,
    const int* __restrict__ bsums, int n)
{
    int i = blockIdx.x * blockDim.x + threadIdx.x;
    if (i == 0) { offsets[0] = 0; cursor[0] = 0; }
    if (i < n) {
        int v = offsets[i + 1] + bsums[i / SCAN_BLK];
        offsets[i + 1] = v;
        cursor[i + 1] = v;
    }
}

__global__ __launch_bounds__(256) void rank_scatter_kernel(
    const int* __restrict__ ei, int E, int* __restrict__ cursor,
    int* __restrict__ sorted_row)
{
    int stride = gridDim.x * blockDim.x;
    for (int e = blockIdx.x * blockDim.x + threadIdx.x; e < E; e += stride) {
        int col = ei[E + e];
        int pos = atomicAdd(&cursor[col], 1);
        sorted_row[pos] = ei[e];
    }
}

// ---------------------------------------------------------------------------
// Aggregate: one wave per node. lane handles 2 floats of the 128-wide row.
// acc = support[n] + sum_{e in CSR[n]} support[sorted_row[e]] + bias.
// Single coalesced write of out; no fp atomics anywhere.
// ---------------------------------------------------------------------------
__global__ __launch_bounds__(256) void aggregate_kernel(
    const float* __restrict__ support, const int* __restrict__ offsets,
    const int* __restrict__ sorted_row, const float* __restrict__ bias,
    float* __restrict__ out)
{
    int wid = (blockIdx.x * blockDim.x + threadIdx.x) >> 6;   // node id
    if (wid >= NUM_NODES) return;
    int j = (threadIdx.x & 63) * 2;

    float2 acc = *reinterpret_cast<const float2*>(support + (size_t)wid * OUT_F + j);
    int e   = offsets[wid];
    int end = offsets[wid + 1];

    // 2-deep unroll for load/add overlap
    for (; e + 1 < end; e += 2) {
        int r0 = sorted_row[e];
        int r1 = sorted_row[e + 1];
        float2 v0 = *reinterpret_cast<const float2*>(support + (size_t)r0 * OUT_F + j);
        float2 v1 = *reinterpret_cast<const float2*>(support + (size_t)r1 * OUT_F + j);
        acc.x += v0.x; acc.y += v0.y;
        acc.x += v1.x; acc.y += v1.y;
    }
    if (e < end) {
        int r0 = sorted_row[e];
        float2 v0 = *reinterpret_cast<const float2*>(support + (size_t)r0 * OUT_F + j);
        acc.x += v0.x; acc.y += v0.y;
    }

    float2 bi = *reinterpret_cast<const float2*>(bias + j);
    acc.x += bi.x; acc.y += bi.y;
    *reinterpret_cast<float2*>(out + (size_t)wid * OUT_F + j) = acc;
}

extern "C" void kernel_launch(void* const* d_in, const int* in_sizes, int n_in,
                              void* d_out, int out_size, void* d_ws, size_t ws_size,
                              hipStream_t stream) {
    const float* x    = (const float*)d_in[0];
    const float* w    = (const float*)d_in[1];
    const float* bias = (const float*)d_in[2];
    const int*   ei   = (const int*)d_in[3];
    float* out = (float*)d_out;
    const int E = in_sizes[3] / 2;
    const int N = NUM_NODES;

    // Workspace layout (ws_size must cover ~58.8 MB):
    //   support    : N*OUT_F floats   = 51.2 MB
    //   counts     : N ints
    //   offsets    : N+1 ints
    //   cursor     : N+1 ints
    //   sorted_row : E ints           = 6.4 MB
    //   bsums      : 128 ints
    float* support  = (float*)d_ws;
    int* counts     = (int*)(support + (size_t)N * OUT_F);
    int* offsets    = counts + N;
    int* cursor     = offsets + N + 1;
    int* sorted_row = cursor + N + 1;
    int* bsums      = sorted_row + E;

    const int nb_scan = (N + SCAN_BLK - 1) / SCAN_BLK;   // 98

    // 1. GEMM: support = X @ W
    gemm_kernel<<<(N + 63) / 64, 256, 0, stream>>>(x, w, support);

    // 2. CSR build
    hipMemsetAsync(counts, 0, (size_t)N * sizeof(int), stream);
    hist_kernel<<<2048, 256, 0, stream>>>(ei, E, counts);
    scan1_kernel<<<nb_scan, 256, 0, stream>>>(counts, offsets, bsums, N);
    scan2_kernel<<<1, 128, 0, stream>>>(bsums, nb_scan);
    scan3_kernel<<<(N + 255) / 256, 256, 0, stream>>>(offsets, cursor, bsums, N);
    rank_scatter_kernel<<<2048, 256, 0, stream>>>(ei, E, cursor, sorted_row);

    // 3. Gather-aggregate, one wave per node
    long long threads = (long long)N * 64;
    aggregate_kernel<<<(int)((threads + 255) / 256), 256, 0, stream>>>(
        support, offsets, sorted_row, bias, out);
}

// Round 3
// 391.062 us; speedup vs baseline: 3.5784x; 1.0979x over previous
//
#include <hip/hip_runtime.h>

#define NUM_NODES 100000
#define IN_F 256
#define OUT_F 128
#define SCAN_BLK 1024   // elements scanned per block in scan1

// bf16 round-to-nearest-even pack of one float (high 16 bits of fp32).
__device__ inline unsigned int f2bf_pair(float lo, float hi) {
    unsigned ulo = __float_as_uint(lo);
    unsigned uhi = __float_as_uint(hi);
    ulo = (ulo + 0x7FFFu + ((ulo >> 16) & 1u)) >> 16;
    uhi = (uhi + 0x7FFFu + ((uhi >> 16) & 1u)) >> 16;
    return ulo | (uhi << 16);
}

// ---------------------------------------------------------------------------
// Kernel 1: support = bf16(X @ W)  (fp32 accumulate, one bf16 rounding)
// Tile 64x128, BK=32, 256 threads, 4x8 per thread.
// ---------------------------------------------------------------------------
__global__ __launch_bounds__(256) void gemm_kernel(
    const float* __restrict__ x, const float* __restrict__ w,
    unsigned int* __restrict__ support_bf)   // N x 64 uints (2 bf16 each)
{
    __shared__ float As[64][33];
    __shared__ float Bs[32][128];

    const int tid = threadIdx.x;
    const int tx = tid & 15;
    const int ty = tid >> 4;
    const int block_row = blockIdx.x * 64;

    float acc[4][8];
#pragma unroll
    for (int i = 0; i < 4; ++i)
#pragma unroll
        for (int j = 0; j < 8; ++j) acc[i][j] = 0.f;

    for (int k0 = 0; k0 < IN_F; k0 += 32) {
#pragma unroll
        for (int i = 0; i < 2; ++i) {
            int idx = tid + i * 256;
            int r = idx >> 3;
            int c4 = (idx & 7) << 2;
            int grow = block_row + r;
            float4 v = {0.f, 0.f, 0.f, 0.f};
            if (grow < NUM_NODES)
                v = *reinterpret_cast<const float4*>(x + (size_t)grow * IN_F + k0 + c4);
            As[r][c4 + 0] = v.x; As[r][c4 + 1] = v.y;
            As[r][c4 + 2] = v.z; As[r][c4 + 3] = v.w;
        }
#pragma unroll
        for (int i = 0; i < 4; ++i) {
            int idx = tid + i * 256;
            int r = idx >> 5;
            int c4 = (idx & 31) << 2;
            *reinterpret_cast<float4*>(&Bs[r][c4]) =
                *reinterpret_cast<const float4*>(w + (size_t)(k0 + r) * OUT_F + c4);
        }
        __syncthreads();

#pragma unroll
        for (int k = 0; k < 32; ++k) {
            float a[4];
#pragma unroll
            for (int i = 0; i < 4; ++i) a[i] = As[ty * 4 + i][k];
            float4 b0 = *reinterpret_cast<const float4*>(&Bs[k][tx * 8]);
            float4 b1 = *reinterpret_cast<const float4*>(&Bs[k][tx * 8 + 4]);
            float b[8] = {b0.x, b0.y, b0.z, b0.w, b1.x, b1.y, b1.z, b1.w};
#pragma unroll
            for (int i = 0; i < 4; ++i)
#pragma unroll
                for (int j = 0; j < 8; ++j)
                    acc[i][j] = fmaf(a[i], b[j], acc[i][j]);
        }
        __syncthreads();
    }

#pragma unroll
    for (int i = 0; i < 4; ++i) {
        int grow = block_row + ty * 4 + i;
        if (grow >= NUM_NODES) continue;
        // 8 floats -> 4 packed uints -> one uint4 store (16B)
        uint4 p;
        p.x = f2bf_pair(acc[i][0], acc[i][1]);
        p.y = f2bf_pair(acc[i][2], acc[i][3]);
        p.z = f2bf_pair(acc[i][4], acc[i][5]);
        p.w = f2bf_pair(acc[i][6], acc[i][7]);
        *reinterpret_cast<uint4*>(support_bf + (size_t)grow * 64 + tx * 4) = p;
    }
}

// ---------------------------------------------------------------------------
// CSR build: histogram -> scan -> rank scatter (int atomics)
// ---------------------------------------------------------------------------
__global__ __launch_bounds__(256) void hist_kernel(
    const int* __restrict__ ei, int E, int* __restrict__ counts)
{
    int stride = gridDim.x * blockDim.x;
    for (int e = blockIdx.x * blockDim.x + threadIdx.x; e < E; e += stride)
        atomicAdd(&counts[ei[E + e]], 1);
}

__global__ __launch_bounds__(256) void scan1_kernel(
    const int* __restrict__ counts, int* __restrict__ offsets,
    int* __restrict__ bsums, int n)
{
    __shared__ int lds[256];
    const int t = threadIdx.x;
    const int base = blockIdx.x * SCAN_BLK + t * 4;
    int v[4];
#pragma unroll
    for (int i = 0; i < 4; ++i) {
        int idx = base + i;
        v[i] = (idx < n) ? counts[idx] : 0;
    }
    v[1] += v[0]; v[2] += v[1]; v[3] += v[2];
    lds[t] = v[3];
    __syncthreads();
    for (int off = 1; off < 256; off <<= 1) {
        int xv = lds[t];
        int yv = (t >= off) ? lds[t - off] : 0;
        __syncthreads();
        lds[t] = xv + yv;
        __syncthreads();
    }
    int prev = (t > 0) ? lds[t - 1] : 0;
#pragma unroll
    for (int i = 0; i < 4; ++i) {
        int idx = base + i;
        if (idx < n) offsets[idx + 1] = v[i] + prev;
    }
    if (t == 255) bsums[blockIdx.x] = lds[255];
}

__global__ __launch_bounds__(128) void scan2_kernel(int* __restrict__ bsums, int nb)
{
    __shared__ int lds[128];
    const int t = threadIdx.x;
    lds[t] = (t < nb) ? bsums[t] : 0;
    __syncthreads();
    for (int off = 1; off < 128; off <<= 1) {
        int xv = lds[t];
        int yv = (t >= off) ? lds[t - off] : 0;
        __syncthreads();
        lds[t] = xv + yv;
        __syncthreads();
    }
    if (t < nb) bsums[t] = (t > 0) ? lds[t - 1] : 0;
}

__global__ __launch_bounds__(256) void scan3_kernel(
    int* __restrict__ offsets, int* __restrict__ cursor,
    const int* __restrict__ bsums, int n)
{
    int i = blockIdx.x * blockDim.x + threadIdx.x;
    if (i == 0) { offsets[0] = 0; cursor[0] = 0; }
    if (i < n) {
        int v = offsets[i + 1] + bsums[i / SCAN_BLK];
        offsets[i + 1] = v;
        cursor[i + 1] = v;
    }
}

__global__ __launch_bounds__(256) void rank_scatter_kernel(
    const int* __restrict__ ei, int E, int* __restrict__ cursor,
    int* __restrict__ sorted_row)
{
    int stride = gridDim.x * blockDim.x;
    for (int e = blockIdx.x * blockDim.x + threadIdx.x; e < E; e += stride) {
        int col = ei[E + e];
        int pos = atomicAdd(&cursor[col], 1);
        sorted_row[pos] = ei[e];
    }
}

// ---------------------------------------------------------------------------
// Aggregate: one wave per node; lane j owns cols [2j, 2j+1] = one packed uint
// per row. acc(fp32) = support[n] + sum support[sorted_row[e]] + bias.
// ---------------------------------------------------------------------------
__global__ __launch_bounds__(256) void aggregate_kernel(
    const unsigned int* __restrict__ support_bf, const int* __restrict__ offsets,
    const int* __restrict__ sorted_row, const float* __restrict__ bias,
    float* __restrict__ out)
{
    int wid = (blockIdx.x * blockDim.x + threadIdx.x) >> 6;   // node id
    if (wid >= NUM_NODES) return;
    int lane = threadIdx.x & 63;

    unsigned int self = support_bf[(size_t)wid * 64 + lane];
    float accx = __uint_as_float(self << 16);
    float accy = __uint_as_float(self & 0xFFFF0000u);

    int e   = offsets[wid];
    int end = offsets[wid + 1];

    // 4-deep unroll for memory-level parallelism
    for (; e + 3 < end; e += 4) {
        int r0 = sorted_row[e];
        int r1 = sorted_row[e + 1];
        int r2 = sorted_row[e + 2];
        int r3 = sorted_row[e + 3];
        unsigned int u0 = support_bf[(size_t)r0 * 64 + lane];
        unsigned int u1 = support_bf[(size_t)r1 * 64 + lane];
        unsigned int u2 = support_bf[(size_t)r2 * 64 + lane];
        unsigned int u3 = support_bf[(size_t)r3 * 64 + lane];
        accx += __uint_as_float(u0 << 16);
        accy += __uint_as_float(u0 & 0xFFFF0000u);
        accx += __uint_as_float(u1 << 16);
        accy += __uint_as_float(u1 & 0xFFFF0000u);
        accx += __uint_as_float(u2 << 16);
        accy += __uint_as_float(u2 & 0xFFFF0000u);
        accx += __uint_as_float(u3 << 16);
        accy += __uint_as_float(u3 & 0xFFFF0000u);
    }
    for (; e < end; ++e) {
        int r0 = sorted_row[e];
        unsigned int u0 = support_bf[(size_t)r0 * 64 + lane];
        accx += __uint_as_float(u0 << 16);
        accy += __uint_as_float(u0 & 0xFFFF0000u);
    }

    float2 bi = *reinterpret_cast<const float2*>(bias + lane * 2);
    float2 o = {accx + bi.x, accy + bi.y};
    *reinterpret_cast<float2*>(out + (size_t)wid * OUT_F + lane * 2) = o;
}

extern "C" void kernel_launch(void* const* d_in, const int* in_sizes, int n_in,
                              void* d_out, int out_size, void* d_ws, size_t ws_size,
                              hipStream_t stream) {
    const float* x    = (const float*)d_in[0];
    const float* w    = (const float*)d_in[1];
    const float* bias = (const float*)d_in[2];
    const int*   ei   = (const int*)d_in[3];
    float* out = (float*)d_out;
    const int E = in_sizes[3] / 2;
    const int N = NUM_NODES;

    // Workspace layout (~33 MB):
    //   support_bf : N*64 uints (bf16x2) = 25.6 MB
    //   counts     : N ints
    //   offsets    : N+1 ints
    //   cursor     : N+1 ints
    //   sorted_row : E ints              = 6.4 MB
    //   bsums      : 128 ints
    unsigned int* support_bf = (unsigned int*)d_ws;
    int* counts     = (int*)(support_bf + (size_t)N * 64);
    int* offsets    = counts + N;
    int* cursor     = offsets + N + 1;
    int* sorted_row = cursor + N + 1;
    int* bsums      = sorted_row + E;

    const int nb_scan = (N + SCAN_BLK - 1) / SCAN_BLK;   // 98

    // 1. GEMM: support = bf16(X @ W)
    gemm_kernel<<<(N + 63) / 64, 256, 0, stream>>>(x, w, support_bf);

    // 2. CSR build
    hipMemsetAsync(counts, 0, (size_t)N * sizeof(int), stream);
    hist_kernel<<<2048, 256, 0, stream>>>(ei, E, counts);
    scan1_kernel<<<nb_scan, 256, 0, stream>>>(counts, offsets, bsums, N);
    scan2_kernel<<<1, 128, 0, stream>>>(bsums, nb_scan);
    scan3_kernel<<<(N + 255) / 256, 256, 0, stream>>>(offsets, cursor, bsums, N);
    rank_scatter_kernel<<<2048, 256, 0, stream>>>(ei, E, cursor, sorted_row);

    // 3. Gather-aggregate, one wave per node
    long long threads = (long long)N * 64;
    aggregate_kernel<<<(int)((threads + 255) / 256), 256, 0, stream>>>(
        support_bf, offsets, sorted_row, bias, out);
}

// Round 4
// 304.332 us; speedup vs baseline: 4.5981x; 1.2850x over previous
//
#include <hip/hip_runtime.h>

#define NUM_NODES 100000
#define IN_F 256
#define OUT_F 128
#define SCAN_BLK 1024   // elements scanned per block in scan1

typedef __attribute__((ext_vector_type(8))) short bf16x8;
typedef __attribute__((ext_vector_type(4))) float f32x4;

// bf16 round-to-nearest-even of one float.
__device__ inline unsigned short f2bf(float f) {
    unsigned u = __float_as_uint(f);
    u = (u + 0x7FFFu + ((u >> 16) & 1u)) >> 16;
    return (unsigned short)u;
}

// ---------------------------------------------------------------------------
// Pre-kernel: WT[n][k] = bf16(W[k][n])  (64 KB, transposed so B-frags are
// contiguous in k)
// ---------------------------------------------------------------------------
__global__ __launch_bounds__(256) void convert_wt_kernel(
    const float* __restrict__ w, unsigned short* __restrict__ wt)
{
    int g = blockIdx.x * 256 + threadIdx.x;      // 0..32767 = k*128+n
    int k = g >> 7, n = g & 127;
    wt[n * 256 + k] = f2bf(w[g]);
}

// ---------------------------------------------------------------------------
// Kernel 1: support = bf16(X @ W) via MFMA.
// 512 threads = 8 waves; each wave one 16-row strip -> 128 rows/block.
// Whole WT (128x256 bf16) in LDS, padded to [128][264] (col stride 528 B).
// A: fp32 direct from global, converted in-register to bf16 fragments.
// ---------------------------------------------------------------------------
__global__ __launch_bounds__(512) void gemm_mfma_kernel(
    const float* __restrict__ x, const unsigned short* __restrict__ wt,
    unsigned short* __restrict__ support_h)
{
    __shared__ unsigned short WT[128][264];

    const int tid = threadIdx.x;

    // Stage WT: 4096 uint4 (16B) chunks, 8 per thread.
    const uint4* src = reinterpret_cast<const uint4*>(wt);
#pragma unroll
    for (int i = 0; i < 8; ++i) {
        int j = tid + i * 512;
        int r = j >> 5;                 // 32 uint4 per 256-elem row
        int c = (j & 31) << 3;          // ushort offset
        *reinterpret_cast<uint4*>(&WT[r][c]) = src[j];
    }
    __syncthreads();

    const int wave = tid >> 6;
    const int lane = tid & 63;
    const int q = lane >> 4;            // 0..3 (k-quarter / row-group)
    const int r16 = lane & 15;          // 0..15
    const int strip_row = blockIdx.x * 128 + wave * 16;

    int arow = strip_row + r16;
    if (arow >= NUM_NODES) arow = NUM_NODES - 1;   // clamp; stores guarded
    const float* xrow = x + (size_t)arow * IN_F + q * 8;

    f32x4 acc[8];
#pragma unroll
    for (int n = 0; n < 8; ++n) acc[n] = (f32x4){0.f, 0.f, 0.f, 0.f};

#pragma unroll
    for (int half = 0; half < 2; ++half) {
        // Prefetch 4 k-steps of A (8 float4 = 32 VGPRs) for MLP.
        float4 a[8];
#pragma unroll
        for (int g = 0; g < 4; ++g) {
            const float* p = xrow + half * 128 + g * 32;
            a[g * 2]     = *reinterpret_cast<const float4*>(p);
            a[g * 2 + 1] = *reinterpret_cast<const float4*>(p + 4);
        }
#pragma unroll
        for (int g = 0; g < 4; ++g) {
            const int k0 = half * 128 + g * 32;
            bf16x8 af;
            af[0] = (short)f2bf(a[g * 2].x);
            af[1] = (short)f2bf(a[g * 2].y);
            af[2] = (short)f2bf(a[g * 2].z);
            af[3] = (short)f2bf(a[g * 2].w);
            af[4] = (short)f2bf(a[g * 2 + 1].x);
            af[5] = (short)f2bf(a[g * 2 + 1].y);
            af[6] = (short)f2bf(a[g * 2 + 1].z);
            af[7] = (short)f2bf(a[g * 2 + 1].w);
#pragma unroll
            for (int n = 0; n < 8; ++n) {
                bf16x8 bfr = *reinterpret_cast<const bf16x8*>(
                    &WT[n * 16 + r16][k0 + q * 8]);
                acc[n] = __builtin_amdgcn_mfma_f32_16x16x32_bf16(
                    af, bfr, acc[n], 0, 0, 0);
            }
        }
    }

    // Epilogue: C/D layout col=lane&15, row=(lane>>4)*4+reg.
#pragma unroll
    for (int n = 0; n < 8; ++n) {
#pragma unroll
        for (int rr = 0; rr < 4; ++rr) {
            int grow = strip_row + q * 4 + rr;
            if (grow < NUM_NODES)
                support_h[(size_t)grow * OUT_F + n * 16 + r16] = f2bf(acc[n][rr]);
        }
    }
}

// ---------------------------------------------------------------------------
// CSR build: histogram -> scan -> rank scatter (int atomics)
// ---------------------------------------------------------------------------
__global__ __launch_bounds__(256) void hist_kernel(
    const int* __restrict__ ei, int E, int* __restrict__ counts)
{
    int stride = gridDim.x * blockDim.x;
    for (int e = blockIdx.x * blockDim.x + threadIdx.x; e < E; e += stride)
        atomicAdd(&counts[ei[E + e]], 1);
}

__global__ __launch_bounds__(256) void scan1_kernel(
    const int* __restrict__ counts, int* __restrict__ offsets,
    int* __restrict__ bsums, int n)
{
    __shared__ int lds[256];
    const int t = threadIdx.x;
    const int base = blockIdx.x * SCAN_BLK + t * 4;
    int v[4];
#pragma unroll
    for (int i = 0; i < 4; ++i) {
        int idx = base + i;
        v[i] = (idx < n) ? counts[idx] : 0;
    }
    v[1] += v[0]; v[2] += v[1]; v[3] += v[2];
    lds[t] = v[3];
    __syncthreads();
    for (int off = 1; off < 256; off <<= 1) {
        int xv = lds[t];
        int yv = (t >= off) ? lds[t - off] : 0;
        __syncthreads();
        lds[t] = xv + yv;
        __syncthreads();
    }
    int prev = (t > 0) ? lds[t - 1] : 0;
#pragma unroll
    for (int i = 0; i < 4; ++i) {
        int idx = base + i;
        if (idx < n) offsets[idx + 1] = v[i] + prev;
    }
    if (t == 255) bsums[blockIdx.x] = lds[255];
}

__global__ __launch_bounds__(128) void scan2_kernel(int* __restrict__ bsums, int nb)
{
    __shared__ int lds[128];
    const int t = threadIdx.x;
    lds[t] = (t < nb) ? bsums[t] : 0;
    __syncthreads();
    for (int off = 1; off < 128; off <<= 1) {
        int xv = lds[t];
        int yv = (t >= off) ? lds[t - off] : 0;
        __syncthreads();
        lds[t] = xv + yv;
        __syncthreads();
    }
    if (t < nb) bsums[t] = (t > 0) ? lds[t - 1] : 0;
}

__global__ __launch_bounds__(256) void scan3_kernel(
    int* __restrict__ offsets, int* __restrict__ cursor,
    const int* __restrict__ bsums, int n)
{
    int i = blockIdx.x * blockDim.x + threadIdx.x;
    if (i == 0) { offsets[0] = 0; cursor[0] = 0; }
    if (i < n) {
        int v = offsets[i + 1] + bsums[i / SCAN_BLK];
        offsets[i + 1] = v;
        cursor[i + 1] = v;
    }
}

__global__ __launch_bounds__(256) void rank_scatter_kernel(
    const int* __restrict__ ei, int E, int* __restrict__ cursor,
    int* __restrict__ sorted_row)
{
    int stride = gridDim.x * blockDim.x;
    for (int e = blockIdx.x * blockDim.x + threadIdx.x; e < E; e += stride) {
        int col = ei[E + e];
        int pos = atomicAdd(&cursor[col], 1);
        sorted_row[pos] = ei[e];
    }
}

// ---------------------------------------------------------------------------
// Aggregate: one wave per node; lane j owns cols [2j, 2j+1] = one packed uint
// per row. acc(fp32) = support[n] + sum support[sorted_row[e]] + bias.
// ---------------------------------------------------------------------------
__global__ __launch_bounds__(256) void aggregate_kernel(
    const unsigned int* __restrict__ support_bf, const int* __restrict__ offsets,
    const int* __restrict__ sorted_row, const float* __restrict__ bias,
    float* __restrict__ out)
{
    int wid = (blockIdx.x * blockDim.x + threadIdx.x) >> 6;   // node id
    if (wid >= NUM_NODES) return;
    int lane = threadIdx.x & 63;

    unsigned int self = support_bf[(size_t)wid * 64 + lane];
    float accx = __uint_as_float(self << 16);
    float accy = __uint_as_float(self & 0xFFFF0000u);

    int e   = offsets[wid];
    int end = offsets[wid + 1];

    for (; e + 3 < end; e += 4) {
        int r0 = sorted_row[e];
        int r1 = sorted_row[e + 1];
        int r2 = sorted_row[e + 2];
        int r3 = sorted_row[e + 3];
        unsigned int u0 = support_bf[(size_t)r0 * 64 + lane];
        unsigned int u1 = support_bf[(size_t)r1 * 64 + lane];
        unsigned int u2 = support_bf[(size_t)r2 * 64 + lane];
        unsigned int u3 = support_bf[(size_t)r3 * 64 + lane];
        accx += __uint_as_float(u0 << 16);
        accy += __uint_as_float(u0 & 0xFFFF0000u);
        accx += __uint_as_float(u1 << 16);
        accy += __uint_as_float(u1 & 0xFFFF0000u);
        accx += __uint_as_float(u2 << 16);
        accy += __uint_as_float(u2 & 0xFFFF0000u);
        accx += __uint_as_float(u3 << 16);
        accy += __uint_as_float(u3 & 0xFFFF0000u);
    }
    for (; e < end; ++e) {
        int r0 = sorted_row[e];
        unsigned int u0 = support_bf[(size_t)r0 * 64 + lane];
        accx += __uint_as_float(u0 << 16);
        accy += __uint_as_float(u0 & 0xFFFF0000u);
    }

    float2 bi = *reinterpret_cast<const float2*>(bias + lane * 2);
    float2 o = {accx + bi.x, accy + bi.y};
    *reinterpret_cast<float2*>(out + (size_t)wid * OUT_F + lane * 2) = o;
}

extern "C" void kernel_launch(void* const* d_in, const int* in_sizes, int n_in,
                              void* d_out, int out_size, void* d_ws, size_t ws_size,
                              hipStream_t stream) {
    const float* x    = (const float*)d_in[0];
    const float* w    = (const float*)d_in[1];
    const float* bias = (const float*)d_in[2];
    const int*   ei   = (const int*)d_in[3];
    float* out = (float*)d_out;
    const int E = in_sizes[3] / 2;
    const int N = NUM_NODES;

    // Workspace layout (~32.2 MB):
    //   support_bf : N*64 uints (bf16x2)   = 25.6 MB
    //   wt_bf      : 128*256 ushorts       = 64 KB
    //   counts     : N ints
    //   offsets    : N+1 ints
    //   cursor     : N+1 ints
    //   sorted_row : E ints                = 6.4 MB
    //   bsums      : 128 ints
    unsigned int* support_bf = (unsigned int*)d_ws;
    unsigned short* wt_bf = (unsigned short*)(support_bf + (size_t)N * 64);
    int* counts     = (int*)(wt_bf + 128 * 256);
    int* offsets    = counts + N;
    int* cursor     = offsets + N + 1;
    int* sorted_row = cursor + N + 1;
    int* bsums      = sorted_row + E;

    const int nb_scan = (N + SCAN_BLK - 1) / SCAN_BLK;   // 98

    // 1. GEMM: support = bf16(X @ W) via MFMA
    convert_wt_kernel<<<128, 256, 0, stream>>>(w, wt_bf);
    gemm_mfma_kernel<<<(N + 127) / 128, 512, 0, stream>>>(
        x, wt_bf, (unsigned short*)support_bf);

    // 2. CSR build
    hipMemsetAsync(counts, 0, (size_t)N * sizeof(int), stream);
    hist_kernel<<<2048, 256, 0, stream>>>(ei, E, counts);
    scan1_kernel<<<nb_scan, 256, 0, stream>>>(counts, offsets, bsums, N);
    scan2_kernel<<<1, 128, 0, stream>>>(bsums, nb_scan);
    scan3_kernel<<<(N + 255) / 256, 256, 0, stream>>>(offsets, cursor, bsums, N);
    rank_scatter_kernel<<<2048, 256, 0, stream>>>(ei, E, cursor, sorted_row);

    // 3. Gather-aggregate, one wave per node
    long long threads = (long long)N * 64;
    aggregate_kernel<<<(int)((threads + 255) / 256), 256, 0, stream>>>(
        support_bf, offsets, sorted_row, bias, out);
}